// Round 11
// baseline (66.339 us; speedup 1.0000x reference)
//
#include <hip/hip_runtime.h>
#include <math.h>

#define BATCH 8
#define SEQ 1024
#define DM 256
#define NH 8
#define DH 32
#define MTOT (BATCH*SEQ)
#define LOG2E 1.4426950408889634f
#define SCALING 5.656854249492381f
#define QSCALE (SCALING * LOG2E)
#define NROW 65536              // 64 bh * 1024 ql
#define OSC 0.0625f             // partial-O scale (f16 headroom); cancels in merge

typedef __attribute__((ext_vector_type(8))) short short8;
typedef __attribute__((ext_vector_type(4))) float f32x4;
typedef _Float16 f16;
typedef __attribute__((ext_vector_type(8))) _Float16 f16x8;
typedef __attribute__((ext_vector_type(4))) _Float16 f16x4;

__device__ inline unsigned short f2bf(float f){
  union { float f; unsigned u; } x; x.f = f;
  unsigned r = x.u + 0x7fffu + ((x.u >> 16) & 1u);
  return (unsigned short)(r >> 16);
}
__device__ inline float bf2f(unsigned short s){
  union { unsigned u; float f; } x; x.u = ((unsigned)s) << 16;
  return x.f;
}
__device__ inline float u2f(unsigned u){
  union { unsigned u; float f; } x; x.u = u; return x.f;
}
__device__ inline unsigned cvtpk_bf16(float a, float b){
  unsigned r;
  asm("v_cvt_pk_bf16_f32 %0, %1, %2" : "=v"(r) : "v"(a), "v"(b));
  return r;  // low16 = bf16(a), high16 = bf16(b)
}
__device__ inline float fast_exp2(float x){
  float r; asm("v_exp_f32 %0, %1" : "=v"(r) : "v"(x)); return r;
}

__device__ inline f32x4 mfma_bf16(short8 a, short8 b, f32x4 c){
  return __builtin_amdgcn_mfma_f32_16x16x32_bf16(a, b, c, 0, 0, 0);
}
__device__ inline f32x4 mfma_f16_32(f16x8 a, f16x8 b, f32x4 c){
  return __builtin_amdgcn_mfma_f32_16x16x32_f16(a, b, c, 0, 0, 0);
}
__device__ inline f32x4 mfma_f16_16(f16x4 a, f16x4 b, f32x4 c){
  return __builtin_amdgcn_mfma_f32_16x16x16f16(a, b, c, 0, 0, 0);
}

// ---- prep: weight arrays --------------------------------------------------
__global__ __launch_bounds__(256) void prep_w_kernel(
    const float* __restrict__ Wq, const float* __restrict__ Wk,
    const float* __restrict__ Wv, const float* __restrict__ Wo,
    unsigned short* __restrict__ wqh, unsigned short* __restrict__ wql,
    unsigned short* __restrict__ wkh, unsigned short* __restrict__ wkl,
    f16* __restrict__ wv16, f16* __restrict__ wo16){
  int i = blockIdx.x * blockDim.x + threadIdx.x;
  if (i < DM * DM){
    float q = Wq[i];
    unsigned short qh_ = f2bf(q);
    wqh[i] = qh_; wql[i] = f2bf(q - bf2f(qh_));
    float k = Wk[i];
    unsigned short kh_ = f2bf(k);
    wkh[i] = kh_; wkl[i] = f2bf(k - bf2f(kh_));
    wv16[i] = (f16)Wv[i];
    wo16[i] = (f16)Wo[i];
  }
}

// ---- fused QKV projection (reads hs/oq f32 directly) + V-transpose --------
__global__ __launch_bounds__(256, 2) void proj_qkv_kernel(
    const float* __restrict__ hs, const float* __restrict__ oq,
    const unsigned short* __restrict__ wqh, const unsigned short* __restrict__ wql,
    const unsigned short* __restrict__ wkh, const unsigned short* __restrict__ wkl,
    const f16* __restrict__ wv16,
    const float* __restrict__ bq, const float* __restrict__ bk, const float* __restrict__ bv,
    unsigned short* __restrict__ qhp, unsigned short* __restrict__ qlp,
    unsigned short* __restrict__ khp, unsigned short* __restrict__ klp,
    f16* __restrict__ vT){
  __shared__ unsigned short XH[128][40];
  __shared__ unsigned short XL[128][40];
  __shared__ f16 XV[128][40];
  __shared__ unsigned short WQH[64][40];
  __shared__ unsigned short WQL[64][40];
  __shared__ unsigned short WKH[64][40];
  __shared__ unsigned short WKL[64][40];
  __shared__ f16 WV[64][40];
  __shared__ f16 VTT[64][144];
  const int tid = threadIdx.x;
  const int lane = tid & 63, wave = tid >> 6;
  const int bid = blockIdx.x;
  const int xcd = bid & 7, g = bid >> 3;
  const int nb = g & 3, mb = xcd * 8 + (g >> 2);
  const int m0 = mb * 128, n0 = nb * 64;
  const int wm = wave >> 1, wn = wave & 1;
  const int r = lane & 15, jj = lane >> 4;

  const int sr = tid >> 2, ssl = (tid & 3) * 8;
  const float* hs0 = hs + (size_t)(m0 + sr) * DM + ssl;
  const float* hs1 = hs0 + 64 * DM;
  const float* oq0 = oq + (size_t)(m0 + sr) * DM + ssl;
  const float* oq1 = oq0 + 64 * DM;
  const size_t wo = (size_t)(n0 + sr) * DM + ssl;

  auto convrow = [&](const float* hp, const float* op, int kk,
                     short8& xh, short8& xl, f16x8& xv){
    f32x4 ha = *(const f32x4*)(hp + kk);
    f32x4 hb = *(const f32x4*)(hp + kk + 4);
    f32x4 oa = *(const f32x4*)(op + kk);
    f32x4 ob = *(const f32x4*)(op + kk + 4);
    float p0 = ha[0]+oa[0], p1 = ha[1]+oa[1], p2 = ha[2]+oa[2], p3 = ha[3]+oa[3];
    float p4 = hb[0]+ob[0], p5 = hb[1]+ob[1], p6 = hb[2]+ob[2], p7 = hb[3]+ob[3];
    union { unsigned u[4]; short8 s; } H, L;
    H.u[0] = cvtpk_bf16(p0, p1); H.u[1] = cvtpk_bf16(p2, p3);
    H.u[2] = cvtpk_bf16(p4, p5); H.u[3] = cvtpk_bf16(p6, p7);
    float l0 = p0 - u2f(H.u[0] << 16), l1 = p1 - u2f(H.u[0] & 0xffff0000u);
    float l2 = p2 - u2f(H.u[1] << 16), l3 = p3 - u2f(H.u[1] & 0xffff0000u);
    float l4 = p4 - u2f(H.u[2] << 16), l5 = p5 - u2f(H.u[2] & 0xffff0000u);
    float l6 = p6 - u2f(H.u[3] << 16), l7 = p7 - u2f(H.u[3] & 0xffff0000u);
    L.u[0] = cvtpk_bf16(l0, l1); L.u[1] = cvtpk_bf16(l2, l3);
    L.u[2] = cvtpk_bf16(l4, l5); L.u[3] = cvtpk_bf16(l6, l7);
    xh = H.s; xl = L.s;
    f16x8 v;
    v[0]=(f16)ha[0]; v[1]=(f16)ha[1]; v[2]=(f16)ha[2]; v[3]=(f16)ha[3];
    v[4]=(f16)hb[0]; v[5]=(f16)hb[1]; v[6]=(f16)hb[2]; v[7]=(f16)hb[3];
    xv = v;
  };

  short8 sxh0, sxh1, sxl0, sxl1, rwq, rwql_, rwk, rwkl_;
  f16x8 sxv0, sxv1, rwv;
  convrow(hs0, oq0, 0, sxh0, sxl0, sxv0);
  convrow(hs1, oq1, 0, sxh1, sxl1, sxv1);
  rwq = *(const short8*)(wqh + wo);   rwql_ = *(const short8*)(wql + wo);
  rwk = *(const short8*)(wkh + wo);   rwkl_ = *(const short8*)(wkl + wo);
  rwv = *(const f16x8*)(wv16 + wo);

  f32x4 aq[4][2], ak[4][2], av[4][2];
#pragma unroll
  for (int mi = 0; mi < 4; ++mi)
#pragma unroll
    for (int ni = 0; ni < 2; ++ni){
      aq[mi][ni] = (f32x4){0.f,0.f,0.f,0.f};
      ak[mi][ni] = (f32x4){0.f,0.f,0.f,0.f};
      av[mi][ni] = (f32x4){0.f,0.f,0.f,0.f};
    }

  for (int kk = 0; kk < DM; kk += 32){
    __syncthreads();
    *(short8*)&XH[sr][ssl] = sxh0;  *(short8*)&XH[sr + 64][ssl] = sxh1;
    *(short8*)&XL[sr][ssl] = sxl0;  *(short8*)&XL[sr + 64][ssl] = sxl1;
    *(f16x8*)&XV[sr][ssl] = sxv0;   *(f16x8*)&XV[sr + 64][ssl] = sxv1;
    *(short8*)&WQH[sr][ssl] = rwq;  *(short8*)&WQL[sr][ssl] = rwql_;
    *(short8*)&WKH[sr][ssl] = rwk;  *(short8*)&WKL[sr][ssl] = rwkl_;
    *(f16x8*)&WV[sr][ssl] = rwv;
    __syncthreads();
    if (kk + 32 < DM){
      const int o = kk + 32;
      convrow(hs0, oq0, o, sxh0, sxl0, sxv0);
      convrow(hs1, oq1, o, sxh1, sxl1, sxv1);
      rwq = *(const short8*)(wqh + wo + o);   rwql_ = *(const short8*)(wql + wo + o);
      rwk = *(const short8*)(wkh + wo + o);   rwkl_ = *(const short8*)(wkl + wo + o);
      rwv = *(const f16x8*)(wv16 + wo + o);
    }
#pragma unroll
    for (int ni = 0; ni < 2; ++ni){
      const int brow = wn * 32 + ni * 16 + r;
      short8 bwqh = *(const short8*)&WQH[brow][jj * 8];
      short8 bwql = *(const short8*)&WQL[brow][jj * 8];
      short8 bwkh = *(const short8*)&WKH[brow][jj * 8];
      short8 bwkl = *(const short8*)&WKL[brow][jj * 8];
      f16x8 bwv = *(const f16x8*)&WV[brow][jj * 8];
      __builtin_amdgcn_s_setprio(1);
#pragma unroll
      for (int mi = 0; mi < 4; ++mi){
        const int arow = wm * 64 + mi * 16 + r;
        short8 axh = *(const short8*)&XH[arow][jj * 8];
        short8 axl = *(const short8*)&XL[arow][jj * 8];
        f16x8 axv = *(const f16x8*)&XV[arow][jj * 8];
        aq[mi][ni] = mfma_bf16(axh, bwqh, aq[mi][ni]);
        aq[mi][ni] = mfma_bf16(axh, bwql, aq[mi][ni]);
        aq[mi][ni] = mfma_bf16(axl, bwqh, aq[mi][ni]);
        ak[mi][ni] = mfma_bf16(axh, bwkh, ak[mi][ni]);
        ak[mi][ni] = mfma_bf16(axh, bwkl, ak[mi][ni]);
        ak[mi][ni] = mfma_bf16(axl, bwkh, ak[mi][ni]);
        av[mi][ni] = mfma_f16_32(axv, bwv, av[mi][ni]);
      }
      __builtin_amdgcn_s_setprio(0);
    }
  }
#pragma unroll
  for (int ni = 0; ni < 2; ++ni){
    const int col = n0 + wn * 32 + ni * 16 + r;
    const float bqc = bq[col] * QSCALE;
    const float bkc = bk[col];
    const float bvc = bv[col];
#pragma unroll
    for (int mi = 0; mi < 4; ++mi){
      f16x4 v4;
#pragma unroll
      for (int rr = 0; rr < 4; ++rr){
        const int row = m0 + wm * 64 + mi * 16 + jj * 4 + rr;
        float qv = aq[mi][ni][rr] * QSCALE + bqc;
        unsigned short qhi = f2bf(qv);
        qhp[row * DM + col] = qhi;
        qlp[row * DM + col] = f2bf(qv - bf2f(qhi));
        float kv = ak[mi][ni][rr] + bkc;
        unsigned short khi = f2bf(kv);
        khp[row * DM + col] = khi;
        klp[row * DM + col] = f2bf(kv - bf2f(khi));
        v4[rr] = (f16)(av[mi][ni][rr] + bvc);
      }
      *(f16x4*)&VTT[wn * 32 + ni * 16 + r][wm * 64 + mi * 16 + jj * 4] = v4;
    }
  }
  __syncthreads();
  const int batch = m0 >> 10;
  const int s0 = m0 & 1023;
  const int c = tid >> 2, sblk = (tid & 3) * 32;
  f16* dst = vT + ((size_t)(batch * DM + n0 + c)) * SEQ + s0 + sblk;
#pragma unroll
  for (int u = 0; u < 4; ++u){
    *(f16x8*)(dst + u * 8) = *(const f16x8*)&VTT[c][sblk + u * 8];
  }
}

// ---- flash attention: key-split x2, 32 q-rows/wave, XCD-pinned, setprio ----
__global__ __launch_bounds__(256, 3) void attn_kernel(
    const unsigned short* __restrict__ qh, const unsigned short* __restrict__ ql,
    const unsigned short* __restrict__ kh, const unsigned short* __restrict__ kl,
    const f16* __restrict__ vT, f16* __restrict__ opart, float* __restrict__ mlpart){
  __shared__ unsigned short KH[2][64][40];
  __shared__ unsigned short KL[2][64][40];
  __shared__ f16 VT[2][32][72];
  const int lane = threadIdx.x & 63;
  const int wave = threadIdx.x >> 6;
  const int tid = threadIdx.x;
  const int xcd = blockIdx.x & 7, j = blockIdx.x >> 3;   // j: 0..127
  const int bh = xcd * 8 + (j & 7);
  const int u = j >> 3;                  // 0..15
  const int qb = u & 7, half = u >> 3;
  const int b = bh >> 3, h = bh & 7;
  const int q0 = (qb * 4 + wave) * 32;
  const int rowbase = b * SEQ;
  const int kbase = rowbase + half * 512;
  const int col0 = h * DH;
  const int r = lane & 15, jj = lane >> 4;

  const int qrowA = rowbase + q0 + r;
  const int qrowB = qrowA + 16;
  short8 bqhA = *(const short8*)(qh + qrowA * DM + col0 + jj * 8);
  short8 bqlA = *(const short8*)(ql + qrowA * DM + col0 + jj * 8);
  short8 bqhB = *(const short8*)(qh + qrowB * DM + col0 + jj * 8);
  short8 bqlB = *(const short8*)(ql + qrowB * DM + col0 + jj * 8);

  const int skey = tid >> 2, ssl = tid & 3;
  const unsigned short* khsrc = kh + (size_t)(kbase + skey) * DM + col0 + ssl * 8;
  const unsigned short* klsrc = kl + (size_t)(kbase + skey) * DM + col0 + ssl * 8;
  const int sdh = tid >> 3, ss8 = tid & 7;
  const f16* vsrc = vT + (size_t)(b * DM + col0 + sdh) * SEQ + half * 512 + ss8 * 8;

  short8 rkh = *(const short8*)(khsrc);
  short8 rkl = *(const short8*)(klsrc);
  f16x8 rv = *(const f16x8*)(vsrc);

  float mA = -INFINITY, lsumA = 0.f;
  float mB = -INFINITY, lsumB = 0.f;
  f32x4 o0a = {0.f,0.f,0.f,0.f}, o1a = {0.f,0.f,0.f,0.f};
  f32x4 o0b = {0.f,0.f,0.f,0.f}, o1b = {0.f,0.f,0.f,0.f};

  for (int c = 0; c < 512; c += 64){
    const int p = (c >> 6) & 1;
    *(short8*)&KH[p][skey][ssl * 8] = rkh;
    *(short8*)&KL[p][skey][ssl * 8] = rkl;
    *(f16x8*)&VT[p][sdh][ss8 * 8] = rv;
    __syncthreads();
    if (c + 64 < 512){
      rkh = *(const short8*)(khsrc + (size_t)(c + 64) * DM);
      rkl = *(const short8*)(klsrc + (size_t)(c + 64) * DM);
      rv = *(const f16x8*)(vsrc + c + 64);
    }
    f32x4 sA[4], sB[4];
    float cmaxA = -INFINITY, cmaxB = -INFINITY;
    __builtin_amdgcn_s_setprio(1);
#pragma unroll
    for (int t = 0; t < 4; ++t){
      short8 akh = *(const short8*)&KH[p][t * 16 + r][jj * 8];
      short8 akl = *(const short8*)&KL[p][t * 16 + r][jj * 8];
      f32x4 sv = {0.f,0.f,0.f,0.f};
      sv = mfma_bf16(akh, bqhA, sv);
      sv = mfma_bf16(akh, bqlA, sv);
      sv = mfma_bf16(akl, bqhA, sv);
      sA[t] = sv;
      cmaxA = fmaxf(cmaxA, fmaxf(fmaxf(sv[0], sv[1]), fmaxf(sv[2], sv[3])));
      f32x4 sw = {0.f,0.f,0.f,0.f};
      sw = mfma_bf16(akh, bqhB, sw);
      sw = mfma_bf16(akh, bqlB, sw);
      sw = mfma_bf16(akl, bqhB, sw);
      sB[t] = sw;
      cmaxB = fmaxf(cmaxB, fmaxf(fmaxf(sw[0], sw[1]), fmaxf(sw[2], sw[3])));
    }
    __builtin_amdgcn_s_setprio(0);
    cmaxA = fmaxf(cmaxA, __shfl_xor(cmaxA, 16, 64));
    cmaxA = fmaxf(cmaxA, __shfl_xor(cmaxA, 32, 64));
    cmaxB = fmaxf(cmaxB, __shfl_xor(cmaxB, 16, 64));
    cmaxB = fmaxf(cmaxB, __shfl_xor(cmaxB, 32, 64));
    if (!__all(cmaxA - mA <= 8.0f)){
      const float mnew = fmaxf(mA, cmaxA);
      const float scale = fast_exp2(mA - mnew);
      lsumA *= scale;
#pragma unroll
      for (int rr = 0; rr < 4; ++rr){ o0a[rr] *= scale; o1a[rr] *= scale; }
      mA = mnew;
    }
    if (!__all(cmaxB - mB <= 8.0f)){
      const float mnew = fmaxf(mB, cmaxB);
      const float scale = fast_exp2(mB - mnew);
      lsumB *= scale;
#pragma unroll
      for (int rr = 0; rr < 4; ++rr){ o0b[rr] *= scale; o1b[rr] *= scale; }
      mB = mnew;
    }
    float psA = 0.f, psB = 0.f;
    f16x4 bpA[4], bpB[4];
#pragma unroll
    for (int t = 0; t < 4; ++t){
      float a0 = fast_exp2(sA[t][0] - mA);
      float a1 = fast_exp2(sA[t][1] - mA);
      float a2 = fast_exp2(sA[t][2] - mA);
      float a3 = fast_exp2(sA[t][3] - mA);
      psA += (a0 + a1) + (a2 + a3);
      f16x4 ba; ba[0]=(f16)a0; ba[1]=(f16)a1; ba[2]=(f16)a2; ba[3]=(f16)a3;
      bpA[t] = ba;
      float b0 = fast_exp2(sB[t][0] - mB);
      float b1 = fast_exp2(sB[t][1] - mB);
      float b2 = fast_exp2(sB[t][2] - mB);
      float b3 = fast_exp2(sB[t][3] - mB);
      psB += (b0 + b1) + (b2 + b3);
      f16x4 bb; bb[0]=(f16)b0; bb[1]=(f16)b1; bb[2]=(f16)b2; bb[3]=(f16)b3;
      bpB[t] = bb;
    }
    psA += __shfl_xor(psA, 16, 64);
    psA += __shfl_xor(psA, 32, 64);
    lsumA += psA;
    psB += __shfl_xor(psB, 16, 64);
    psB += __shfl_xor(psB, 32, 64);
    lsumB += psB;
    __builtin_amdgcn_s_setprio(1);
#pragma unroll
    for (int t = 0; t < 4; ++t){
      f16x4 av0 = *(const f16x4*)&VT[p][r][t * 16 + jj * 4];
      f16x4 av1 = *(const f16x4*)&VT[p][16 + r][t * 16 + jj * 4];
      o0a = mfma_f16_16(av0, bpA[t], o0a);
      o1a = mfma_f16_16(av1, bpA[t], o1a);
      o0b = mfma_f16_16(av0, bpB[t], o0b);
      o1b = mfma_f16_16(av1, bpB[t], o1b);
    }
    __builtin_amdgcn_s_setprio(0);
  }
  const size_t prowA = (size_t)(half * NROW + bh * 1024 + q0 + r);
  const size_t prowB = prowA + 16;
  f16x4 w0a, w1a, w0b, w1b;
#pragma unroll
  for (int rr = 0; rr < 4; ++rr){
    w0a[rr] = (f16)(o0a[rr] * OSC); w1a[rr] = (f16)(o1a[rr] * OSC);
    w0b[rr] = (f16)(o0b[rr] * OSC); w1b[rr] = (f16)(o1b[rr] * OSC);
  }
  *(f16x4*)(opart + prowA * 32 + jj * 4) = w0a;
  *(f16x4*)(opart + prowA * 32 + 16 + jj * 4) = w1a;
  *(f16x4*)(opart + prowB * 32 + jj * 4) = w0b;
  *(f16x4*)(opart + prowB * 32 + 16 + jj * 4) = w1b;
  if (jj == 0){
    ((float2*)mlpart)[prowA] = make_float2(mA, lsumA * OSC);
    ((float2*)mlpart)[prowB] = make_float2(mB, lsumB * OSC);
  }
}

// ---- output projection with fused key-half merge ---------------------------
// Merge coefficients (s1,s2,inv) precomputed once per (row,head) into LDS.
__global__ __launch_bounds__(256, 4) void oproj_kernel(
    const f16* __restrict__ opart, const float* __restrict__ mlpart,
    const f16* __restrict__ wo16,
    const float* __restrict__ bo, float* __restrict__ out){
  __shared__ f16 AT[64][40];
  __shared__ f16 WO[64][40];
  __shared__ float MS[64][8][3];
  const int tid = threadIdx.x;
  const int lane = tid & 63, wave = tid >> 6;
  const int bid = blockIdx.x;
  const int xcd = bid & 7, g = bid >> 3;            // 512 blocks
  const int nb = g & 3, mb = xcd * 16 + (g >> 2);   // mb 0..127
  const int m0 = mb * 64, n0 = nb * 64;
  const int wm = wave >> 1, wn = wave & 1;
  const int r = lane & 15, jj = lane >> 4;
  const int sr = tid >> 2, ssl = (tid & 3) * 8;
  const int arow = m0 + sr;
  const int ab = arow >> 10, as = arow & 1023;
  const size_t rpbase = (size_t)ab * 8 * 1024 + as;   // + h*1024
  const f16* wsrc = wo16 + (size_t)(n0 + sr) * DM + ssl;

  // precompute merge coefficients: 512 (row,h) pairs, 2 per thread
#pragma unroll
  for (int q = 0; q < 2; ++q){
    const int idx = tid * 2 + q;
    const int prow = idx >> 3, ph = idx & 7;
    const int garow = m0 + prow;
    const size_t rp = (size_t)(garow >> 10) * 8 * 1024 + (garow & 1023)
                      + (size_t)ph * 1024;
    const float2 ml1 = ((const float2*)mlpart)[rp];
    const float2 ml2 = ((const float2*)mlpart)[NROW + rp];
    const float M = fmaxf(ml1.x, ml2.x);
    const float s1 = fast_exp2(ml1.x - M);
    const float s2 = fast_exp2(ml2.x - M);
    const float inv = 1.f / (ml1.y * s1 + ml2.y * s2);
    MS[prow][ph][0] = s1 * inv;
    MS[prow][ph][1] = s2 * inv;
  }
  __syncthreads();

  auto mload = [&](int kk) -> f16x8 {
    const int h = kk >> 5;
    const size_t rp = rpbase + (size_t)h * 1024;
    const float c1 = MS[sr][h][0];
    const float c2 = MS[sr][h][1];
    f16x8 o1 = *(const f16x8*)(opart + rp * 32 + ssl);
    f16x8 o2 = *(const f16x8*)(opart + ((size_t)NROW + rp) * 32 + ssl);
    f16x8 o;
#pragma unroll
    for (int q = 0; q < 8; ++q)
      o[q] = (f16)((float)o1[q] * c1 + (float)o2[q] * c2);
    return o;
  };

  f16x8 ra = mload(0);
  f16x8 rw = *(const f16x8*)(wsrc);
  f32x4 acc[2][2];
#pragma unroll
  for (int mi = 0; mi < 2; ++mi){
    acc[mi][0] = (f32x4){0.f,0.f,0.f,0.f};
    acc[mi][1] = (f32x4){0.f,0.f,0.f,0.f};
  }
  for (int kk = 0; kk < DM; kk += 32){
    __syncthreads();
    *(f16x8*)&AT[sr][ssl] = ra;
    *(f16x8*)&WO[sr][ssl] = rw;
    __syncthreads();
    if (kk + 32 < DM){
      ra = mload(kk + 32);
      rw = *(const f16x8*)(wsrc + kk + 32);
    }
    f16x8 bf0 = *(const f16x8*)&WO[wn * 32 + r][jj * 8];
    f16x8 bf1 = *(const f16x8*)&WO[wn * 32 + 16 + r][jj * 8];
    __builtin_amdgcn_s_setprio(1);
#pragma unroll
    for (int mi = 0; mi < 2; ++mi){
      f16x8 af = *(const f16x8*)&AT[wm * 32 + mi * 16 + r][jj * 8];
      acc[mi][0] = mfma_f16_32(af, bf0, acc[mi][0]);
      acc[mi][1] = mfma_f16_32(af, bf1, acc[mi][1]);
    }
    __builtin_amdgcn_s_setprio(0);
  }
#pragma unroll
  for (int ni = 0; ni < 2; ++ni){
    const int col = n0 + wn * 32 + ni * 16 + r;
    const float bc = bo[col];
#pragma unroll
    for (int mi = 0; mi < 2; ++mi){
#pragma unroll
      for (int rr = 0; rr < 4; ++rr){
        const int row = m0 + wm * 32 + mi * 16 + jj * 4 + rr;
        out[row * DM + col] = acc[mi][ni][rr] + bc;
      }
    }
  }
}

extern "C" void kernel_launch(void* const* d_in, const int* in_sizes, int n_in,
                              void* d_out, int out_size, void* d_ws, size_t ws_size,
                              hipStream_t stream){
  const float* hs = (const float*)d_in[0];
  const float* oq = (const float*)d_in[1];
  const float* Wq = (const float*)d_in[2];
  const float* bq = (const float*)d_in[3];
  const float* Wk = (const float*)d_in[4];
  const float* bk = (const float*)d_in[5];
  const float* Wv = (const float*)d_in[6];
  const float* bv = (const float*)d_in[7];
  const float* Wo = (const float*)d_in[8];
  const float* bo = (const float*)d_in[9];
  float* out = (float*)d_out;

  char* p = (char*)d_ws;
  auto alloc = [&](size_t bytes) -> char* {
    char* r = p;
    p += (bytes + 255) & ~((size_t)255);
    return r;
  };
  const size_t xb = (size_t)MTOT * DM * 2;  // 4 MiB per bf16/f16 plane
  unsigned short* qh = (unsigned short*)alloc(xb);
  unsigned short* ql = (unsigned short*)alloc(xb);
  unsigned short* kh = (unsigned short*)alloc(xb);
  unsigned short* kl = (unsigned short*)alloc(xb);
  f16* vT = (f16*)alloc(xb);
  const size_t wb = (size_t)DM * DM * 2;  // 128 KiB per weight plane
  unsigned short* wqh = (unsigned short*)alloc(wb);
  unsigned short* wql = (unsigned short*)alloc(wb);
  unsigned short* wkh = (unsigned short*)alloc(wb);
  unsigned short* wkl = (unsigned short*)alloc(wb);
  f16* wv16 = (f16*)alloc(wb);
  f16* wo16 = (f16*)alloc(wb);
  f16* opart = (f16*)alloc((size_t)2 * NROW * 32 * 2);      // 8 MiB
  float* mlpart = (float*)alloc((size_t)2 * NROW * 2 * 4);  // 1 MiB

  hipLaunchKernelGGL(prep_w_kernel, dim3(DM * DM / 256), dim3(256), 0, stream,
                     Wq, Wk, Wv, Wo, wqh, wql, wkh, wkl, wv16, wo16);
  hipLaunchKernelGGL(proj_qkv_kernel, dim3(256), dim3(256), 0, stream,
                     hs, oq, wqh, wql, wkh, wkl, wv16, bq, bk, bv,
                     qh, ql, kh, kl, vT);
  hipLaunchKernelGGL(attn_kernel, dim3(1024), dim3(256), 0, stream,
                     qh, ql, kh, kl, vT, opart, mlpart);
  hipLaunchKernelGGL(oproj_kernel, dim3(512), dim3(256), 0, stream,
                     opart, mlpart, wo16, bo, out);
}

// Round 12
// 65.224 us; speedup vs baseline: 1.0171x; 1.0171x over previous
//
#include <hip/hip_runtime.h>
#include <math.h>

#define BATCH 8
#define SEQ 1024
#define DM 256
#define NH 8
#define DH 32
#define MTOT (BATCH*SEQ)
#define LOG2E 1.4426950408889634f
#define SCALING 5.656854249492381f
#define QSCALE (SCALING * LOG2E)
#define NROW 65536              // 64 bh * 1024 ql
#define OSC 0.0625f             // partial-O scale (f16 headroom); cancels in merge

typedef __attribute__((ext_vector_type(8))) short short8;
typedef __attribute__((ext_vector_type(4))) float f32x4;
typedef _Float16 f16;
typedef __attribute__((ext_vector_type(8))) _Float16 f16x8;
typedef __attribute__((ext_vector_type(4))) _Float16 f16x4;

__device__ inline unsigned short f2bf(float f){
  union { float f; unsigned u; } x; x.f = f;
  unsigned r = x.u + 0x7fffu + ((x.u >> 16) & 1u);
  return (unsigned short)(r >> 16);
}
__device__ inline float bf2f(unsigned short s){
  union { unsigned u; float f; } x; x.u = ((unsigned)s) << 16;
  return x.f;
}
__device__ inline float u2f(unsigned u){
  union { unsigned u; float f; } x; x.u = u; return x.f;
}
__device__ inline unsigned cvtpk_bf16(float a, float b){
  unsigned r;
  asm("v_cvt_pk_bf16_f32 %0, %1, %2" : "=v"(r) : "v"(a), "v"(b));
  return r;  // low16 = bf16(a), high16 = bf16(b)
}
__device__ inline float fast_exp2(float x){
  float r; asm("v_exp_f32 %0, %1" : "=v"(r) : "v"(x)); return r;
}

__device__ inline f32x4 mfma_bf16(short8 a, short8 b, f32x4 c){
  return __builtin_amdgcn_mfma_f32_16x16x32_bf16(a, b, c, 0, 0, 0);
}
__device__ inline f32x4 mfma_f16_32(f16x8 a, f16x8 b, f32x4 c){
  return __builtin_amdgcn_mfma_f32_16x16x32_f16(a, b, c, 0, 0, 0);
}
__device__ inline f32x4 mfma_f16_16(f16x4 a, f16x4 b, f32x4 c){
  return __builtin_amdgcn_mfma_f32_16x16x16f16(a, b, c, 0, 0, 0);
}

// ---- prep: weight arrays --------------------------------------------------
__global__ __launch_bounds__(256) void prep_w_kernel(
    const float* __restrict__ Wq, const float* __restrict__ Wk,
    const float* __restrict__ Wv, const float* __restrict__ Wo,
    unsigned short* __restrict__ wqh, unsigned short* __restrict__ wql,
    unsigned short* __restrict__ wkh, unsigned short* __restrict__ wkl,
    f16* __restrict__ wv16, f16* __restrict__ wo16){
  int i = blockIdx.x * blockDim.x + threadIdx.x;
  if (i < DM * DM){
    float q = Wq[i];
    unsigned short qh_ = f2bf(q);
    wqh[i] = qh_; wql[i] = f2bf(q - bf2f(qh_));
    float k = Wk[i];
    unsigned short kh_ = f2bf(k);
    wkh[i] = kh_; wkl[i] = f2bf(k - bf2f(kh_));
    wv16[i] = (f16)Wv[i];
    wo16[i] = (f16)Wo[i];
  }
}

// ---- fused QKV projection (reads hs/oq f32 directly) + V-transpose --------
__global__ __launch_bounds__(256, 2) void proj_qkv_kernel(
    const float* __restrict__ hs, const float* __restrict__ oq,
    const unsigned short* __restrict__ wqh, const unsigned short* __restrict__ wql,
    const unsigned short* __restrict__ wkh, const unsigned short* __restrict__ wkl,
    const f16* __restrict__ wv16,
    const float* __restrict__ bq, const float* __restrict__ bk, const float* __restrict__ bv,
    unsigned short* __restrict__ qhp, unsigned short* __restrict__ qlp,
    unsigned short* __restrict__ khp, unsigned short* __restrict__ klp,
    f16* __restrict__ vT){
  __shared__ unsigned short XH[128][40];
  __shared__ unsigned short XL[128][40];
  __shared__ f16 XV[128][40];
  __shared__ unsigned short WQH[64][40];
  __shared__ unsigned short WQL[64][40];
  __shared__ unsigned short WKH[64][40];
  __shared__ unsigned short WKL[64][40];
  __shared__ f16 WV[64][40];
  __shared__ f16 VTT[64][144];
  const int tid = threadIdx.x;
  const int lane = tid & 63, wave = tid >> 6;
  const int bid = blockIdx.x;
  const int xcd = bid & 7, g = bid >> 3;
  const int nb = g & 3, mb = xcd * 8 + (g >> 2);
  const int m0 = mb * 128, n0 = nb * 64;
  const int wm = wave >> 1, wn = wave & 1;
  const int r = lane & 15, jj = lane >> 4;

  const int sr = tid >> 2, ssl = (tid & 3) * 8;
  const float* hs0 = hs + (size_t)(m0 + sr) * DM + ssl;
  const float* hs1 = hs0 + 64 * DM;
  const float* oq0 = oq + (size_t)(m0 + sr) * DM + ssl;
  const float* oq1 = oq0 + 64 * DM;
  const size_t wo = (size_t)(n0 + sr) * DM + ssl;

  auto convrow = [&](const float* hp, const float* op, int kk,
                     short8& xh, short8& xl, f16x8& xv){
    f32x4 ha = *(const f32x4*)(hp + kk);
    f32x4 hb = *(const f32x4*)(hp + kk + 4);
    f32x4 oa = *(const f32x4*)(op + kk);
    f32x4 ob = *(const f32x4*)(op + kk + 4);
    float p0 = ha[0]+oa[0], p1 = ha[1]+oa[1], p2 = ha[2]+oa[2], p3 = ha[3]+oa[3];
    float p4 = hb[0]+ob[0], p5 = hb[1]+ob[1], p6 = hb[2]+ob[2], p7 = hb[3]+ob[3];
    union { unsigned u[4]; short8 s; } H, L;
    H.u[0] = cvtpk_bf16(p0, p1); H.u[1] = cvtpk_bf16(p2, p3);
    H.u[2] = cvtpk_bf16(p4, p5); H.u[3] = cvtpk_bf16(p6, p7);
    float l0 = p0 - u2f(H.u[0] << 16), l1 = p1 - u2f(H.u[0] & 0xffff0000u);
    float l2 = p2 - u2f(H.u[1] << 16), l3 = p3 - u2f(H.u[1] & 0xffff0000u);
    float l4 = p4 - u2f(H.u[2] << 16), l5 = p5 - u2f(H.u[2] & 0xffff0000u);
    float l6 = p6 - u2f(H.u[3] << 16), l7 = p7 - u2f(H.u[3] & 0xffff0000u);
    L.u[0] = cvtpk_bf16(l0, l1); L.u[1] = cvtpk_bf16(l2, l3);
    L.u[2] = cvtpk_bf16(l4, l5); L.u[3] = cvtpk_bf16(l6, l7);
    xh = H.s; xl = L.s;
    f16x8 v;
    v[0]=(f16)ha[0]; v[1]=(f16)ha[1]; v[2]=(f16)ha[2]; v[3]=(f16)ha[3];
    v[4]=(f16)hb[0]; v[5]=(f16)hb[1]; v[6]=(f16)hb[2]; v[7]=(f16)hb[3];
    xv = v;
  };

  short8 sxh0, sxh1, sxl0, sxl1, rwq, rwql_, rwk, rwkl_;
  f16x8 sxv0, sxv1, rwv;
  convrow(hs0, oq0, 0, sxh0, sxl0, sxv0);
  convrow(hs1, oq1, 0, sxh1, sxl1, sxv1);
  rwq = *(const short8*)(wqh + wo);   rwql_ = *(const short8*)(wql + wo);
  rwk = *(const short8*)(wkh + wo);   rwkl_ = *(const short8*)(wkl + wo);
  rwv = *(const f16x8*)(wv16 + wo);

  f32x4 aq[4][2], ak[4][2], av[4][2];
#pragma unroll
  for (int mi = 0; mi < 4; ++mi)
#pragma unroll
    for (int ni = 0; ni < 2; ++ni){
      aq[mi][ni] = (f32x4){0.f,0.f,0.f,0.f};
      ak[mi][ni] = (f32x4){0.f,0.f,0.f,0.f};
      av[mi][ni] = (f32x4){0.f,0.f,0.f,0.f};
    }

  for (int kk = 0; kk < DM; kk += 32){
    __syncthreads();
    *(short8*)&XH[sr][ssl] = sxh0;  *(short8*)&XH[sr + 64][ssl] = sxh1;
    *(short8*)&XL[sr][ssl] = sxl0;  *(short8*)&XL[sr + 64][ssl] = sxl1;
    *(f16x8*)&XV[sr][ssl] = sxv0;   *(f16x8*)&XV[sr + 64][ssl] = sxv1;
    *(short8*)&WQH[sr][ssl] = rwq;  *(short8*)&WQL[sr][ssl] = rwql_;
    *(short8*)&WKH[sr][ssl] = rwk;  *(short8*)&WKL[sr][ssl] = rwkl_;
    *(f16x8*)&WV[sr][ssl] = rwv;
    __syncthreads();
    if (kk + 32 < DM){
      const int o = kk + 32;
      convrow(hs0, oq0, o, sxh0, sxl0, sxv0);
      convrow(hs1, oq1, o, sxh1, sxl1, sxv1);
      rwq = *(const short8*)(wqh + wo + o);   rwql_ = *(const short8*)(wql + wo + o);
      rwk = *(const short8*)(wkh + wo + o);   rwkl_ = *(const short8*)(wkl + wo + o);
      rwv = *(const f16x8*)(wv16 + wo + o);
    }
#pragma unroll
    for (int ni = 0; ni < 2; ++ni){
      const int brow = wn * 32 + ni * 16 + r;
      short8 bwqh = *(const short8*)&WQH[brow][jj * 8];
      short8 bwql = *(const short8*)&WQL[brow][jj * 8];
      short8 bwkh = *(const short8*)&WKH[brow][jj * 8];
      short8 bwkl = *(const short8*)&WKL[brow][jj * 8];
      f16x8 bwv = *(const f16x8*)&WV[brow][jj * 8];
#pragma unroll
      for (int mi = 0; mi < 4; ++mi){
        const int arow = wm * 64 + mi * 16 + r;
        short8 axh = *(const short8*)&XH[arow][jj * 8];
        short8 axl = *(const short8*)&XL[arow][jj * 8];
        f16x8 axv = *(const f16x8*)&XV[arow][jj * 8];
        aq[mi][ni] = mfma_bf16(axh, bwqh, aq[mi][ni]);
        aq[mi][ni] = mfma_bf16(axh, bwql, aq[mi][ni]);
        aq[mi][ni] = mfma_bf16(axl, bwqh, aq[mi][ni]);
        ak[mi][ni] = mfma_bf16(axh, bwkh, ak[mi][ni]);
        ak[mi][ni] = mfma_bf16(axh, bwkl, ak[mi][ni]);
        ak[mi][ni] = mfma_bf16(axl, bwkh, ak[mi][ni]);
        av[mi][ni] = mfma_f16_32(axv, bwv, av[mi][ni]);
      }
    }
  }
#pragma unroll
  for (int ni = 0; ni < 2; ++ni){
    const int col = n0 + wn * 32 + ni * 16 + r;
    const float bqc = bq[col] * QSCALE;
    const float bkc = bk[col];
    const float bvc = bv[col];
#pragma unroll
    for (int mi = 0; mi < 4; ++mi){
      f16x4 v4;
#pragma unroll
      for (int rr = 0; rr < 4; ++rr){
        const int row = m0 + wm * 64 + mi * 16 + jj * 4 + rr;
        float qv = aq[mi][ni][rr] * QSCALE + bqc;
        unsigned short qhi = f2bf(qv);
        qhp[row * DM + col] = qhi;
        qlp[row * DM + col] = f2bf(qv - bf2f(qhi));
        float kv = ak[mi][ni][rr] + bkc;
        unsigned short khi = f2bf(kv);
        khp[row * DM + col] = khi;
        klp[row * DM + col] = f2bf(kv - bf2f(khi));
        v4[rr] = (f16)(av[mi][ni][rr] + bvc);
      }
      *(f16x4*)&VTT[wn * 32 + ni * 16 + r][wm * 64 + mi * 16 + jj * 4] = v4;
    }
  }
  __syncthreads();
  const int batch = m0 >> 10;
  const int s0 = m0 & 1023;
  const int c = tid >> 2, sblk = (tid & 3) * 32;
  f16* dst = vT + ((size_t)(batch * DM + n0 + c)) * SEQ + s0 + sblk;
#pragma unroll
  for (int u = 0; u < 4; ++u){
    *(f16x8*)(dst + u * 8) = *(const f16x8*)&VTT[c][sblk + u * 8];
  }
}

// ---- flash attention: key-split x2, 32 q-rows/wave, XCD-pinned ------------
__global__ __launch_bounds__(256, 3) void attn_kernel(
    const unsigned short* __restrict__ qh, const unsigned short* __restrict__ ql,
    const unsigned short* __restrict__ kh, const unsigned short* __restrict__ kl,
    const f16* __restrict__ vT, f16* __restrict__ opart, float* __restrict__ mlpart){
  __shared__ unsigned short KH[2][64][40];
  __shared__ unsigned short KL[2][64][40];
  __shared__ f16 VT[2][32][72];
  const int lane = threadIdx.x & 63;
  const int wave = threadIdx.x >> 6;
  const int tid = threadIdx.x;
  const int xcd = blockIdx.x & 7, j = blockIdx.x >> 3;   // j: 0..127
  const int bh = xcd * 8 + (j & 7);
  const int u = j >> 3;                  // 0..15
  const int qb = u & 7, half = u >> 3;
  const int b = bh >> 3, h = bh & 7;
  const int q0 = (qb * 4 + wave) * 32;
  const int rowbase = b * SEQ;
  const int kbase = rowbase + half * 512;
  const int col0 = h * DH;
  const int r = lane & 15, jj = lane >> 4;

  const int qrowA = rowbase + q0 + r;
  const int qrowB = qrowA + 16;
  short8 bqhA = *(const short8*)(qh + qrowA * DM + col0 + jj * 8);
  short8 bqlA = *(const short8*)(ql + qrowA * DM + col0 + jj * 8);
  short8 bqhB = *(const short8*)(qh + qrowB * DM + col0 + jj * 8);
  short8 bqlB = *(const short8*)(ql + qrowB * DM + col0 + jj * 8);

  const int skey = tid >> 2, ssl = tid & 3;
  const unsigned short* khsrc = kh + (size_t)(kbase + skey) * DM + col0 + ssl * 8;
  const unsigned short* klsrc = kl + (size_t)(kbase + skey) * DM + col0 + ssl * 8;
  const int sdh = tid >> 3, ss8 = tid & 7;
  const f16* vsrc = vT + (size_t)(b * DM + col0 + sdh) * SEQ + half * 512 + ss8 * 8;

  short8 rkh = *(const short8*)(khsrc);
  short8 rkl = *(const short8*)(klsrc);
  f16x8 rv = *(const f16x8*)(vsrc);

  float mA = -INFINITY, lsumA = 0.f;
  float mB = -INFINITY, lsumB = 0.f;
  f32x4 o0a = {0.f,0.f,0.f,0.f}, o1a = {0.f,0.f,0.f,0.f};
  f32x4 o0b = {0.f,0.f,0.f,0.f}, o1b = {0.f,0.f,0.f,0.f};

  for (int c = 0; c < 512; c += 64){
    const int p = (c >> 6) & 1;
    *(short8*)&KH[p][skey][ssl * 8] = rkh;
    *(short8*)&KL[p][skey][ssl * 8] = rkl;
    *(f16x8*)&VT[p][sdh][ss8 * 8] = rv;
    __syncthreads();
    if (c + 64 < 512){
      rkh = *(const short8*)(khsrc + (size_t)(c + 64) * DM);
      rkl = *(const short8*)(klsrc + (size_t)(c + 64) * DM);
      rv = *(const f16x8*)(vsrc + c + 64);
    }
    f32x4 sA[4], sB[4];
    float cmaxA = -INFINITY, cmaxB = -INFINITY;
#pragma unroll
    for (int t = 0; t < 4; ++t){
      short8 akh = *(const short8*)&KH[p][t * 16 + r][jj * 8];
      short8 akl = *(const short8*)&KL[p][t * 16 + r][jj * 8];
      f32x4 sv = {0.f,0.f,0.f,0.f};
      sv = mfma_bf16(akh, bqhA, sv);
      sv = mfma_bf16(akh, bqlA, sv);
      sv = mfma_bf16(akl, bqhA, sv);
      sA[t] = sv;
      cmaxA = fmaxf(cmaxA, fmaxf(fmaxf(sv[0], sv[1]), fmaxf(sv[2], sv[3])));
      f32x4 sw = {0.f,0.f,0.f,0.f};
      sw = mfma_bf16(akh, bqhB, sw);
      sw = mfma_bf16(akh, bqlB, sw);
      sw = mfma_bf16(akl, bqhB, sw);
      sB[t] = sw;
      cmaxB = fmaxf(cmaxB, fmaxf(fmaxf(sw[0], sw[1]), fmaxf(sw[2], sw[3])));
    }
    cmaxA = fmaxf(cmaxA, __shfl_xor(cmaxA, 16, 64));
    cmaxA = fmaxf(cmaxA, __shfl_xor(cmaxA, 32, 64));
    cmaxB = fmaxf(cmaxB, __shfl_xor(cmaxB, 16, 64));
    cmaxB = fmaxf(cmaxB, __shfl_xor(cmaxB, 32, 64));
    if (!__all(cmaxA - mA <= 8.0f)){
      const float mnew = fmaxf(mA, cmaxA);
      const float scale = fast_exp2(mA - mnew);
      lsumA *= scale;
#pragma unroll
      for (int rr = 0; rr < 4; ++rr){ o0a[rr] *= scale; o1a[rr] *= scale; }
      mA = mnew;
    }
    if (!__all(cmaxB - mB <= 8.0f)){
      const float mnew = fmaxf(mB, cmaxB);
      const float scale = fast_exp2(mB - mnew);
      lsumB *= scale;
#pragma unroll
      for (int rr = 0; rr < 4; ++rr){ o0b[rr] *= scale; o1b[rr] *= scale; }
      mB = mnew;
    }
    float psA = 0.f, psB = 0.f;
    f16x4 bpA[4], bpB[4];
#pragma unroll
    for (int t = 0; t < 4; ++t){
      float a0 = fast_exp2(sA[t][0] - mA);
      float a1 = fast_exp2(sA[t][1] - mA);
      float a2 = fast_exp2(sA[t][2] - mA);
      float a3 = fast_exp2(sA[t][3] - mA);
      psA += (a0 + a1) + (a2 + a3);
      f16x4 ba; ba[0]=(f16)a0; ba[1]=(f16)a1; ba[2]=(f16)a2; ba[3]=(f16)a3;
      bpA[t] = ba;
      float b0 = fast_exp2(sB[t][0] - mB);
      float b1 = fast_exp2(sB[t][1] - mB);
      float b2 = fast_exp2(sB[t][2] - mB);
      float b3 = fast_exp2(sB[t][3] - mB);
      psB += (b0 + b1) + (b2 + b3);
      f16x4 bb; bb[0]=(f16)b0; bb[1]=(f16)b1; bb[2]=(f16)b2; bb[3]=(f16)b3;
      bpB[t] = bb;
    }
    psA += __shfl_xor(psA, 16, 64);
    psA += __shfl_xor(psA, 32, 64);
    lsumA += psA;
    psB += __shfl_xor(psB, 16, 64);
    psB += __shfl_xor(psB, 32, 64);
    lsumB += psB;
#pragma unroll
    for (int t = 0; t < 4; ++t){
      f16x4 av0 = *(const f16x4*)&VT[p][r][t * 16 + jj * 4];
      f16x4 av1 = *(const f16x4*)&VT[p][16 + r][t * 16 + jj * 4];
      o0a = mfma_f16_16(av0, bpA[t], o0a);
      o1a = mfma_f16_16(av1, bpA[t], o1a);
      o0b = mfma_f16_16(av0, bpB[t], o0b);
      o1b = mfma_f16_16(av1, bpB[t], o1b);
    }
  }
  const size_t prowA = (size_t)(half * NROW + bh * 1024 + q0 + r);
  const size_t prowB = prowA + 16;
  f16x4 w0a, w1a, w0b, w1b;
#pragma unroll
  for (int rr = 0; rr < 4; ++rr){
    w0a[rr] = (f16)(o0a[rr] * OSC); w1a[rr] = (f16)(o1a[rr] * OSC);
    w0b[rr] = (f16)(o0b[rr] * OSC); w1b[rr] = (f16)(o1b[rr] * OSC);
  }
  *(f16x4*)(opart + prowA * 32 + jj * 4) = w0a;
  *(f16x4*)(opart + prowA * 32 + 16 + jj * 4) = w1a;
  *(f16x4*)(opart + prowB * 32 + jj * 4) = w0b;
  *(f16x4*)(opart + prowB * 32 + 16 + jj * 4) = w1b;
  if (jj == 0){
    ((float2*)mlpart)[prowA] = make_float2(mA, lsumA * OSC);
    ((float2*)mlpart)[prowB] = make_float2(mB, lsumB * OSC);
  }
}

// ---- output projection with fused key-half merge ---------------------------
// A-tile chunk [kk,kk+32) = head h=kk>>5's 32 dh for row (b,s): merge the two
// opart halves in-register during staging (no intermediate attn buffer).
__global__ __launch_bounds__(256, 4) void oproj_kernel(
    const f16* __restrict__ opart, const float* __restrict__ mlpart,
    const f16* __restrict__ wo16,
    const float* __restrict__ bo, float* __restrict__ out){
  __shared__ f16 AT[64][40];
  __shared__ f16 WO[64][40];
  const int tid = threadIdx.x;
  const int lane = tid & 63, wave = tid >> 6;
  const int bid = blockIdx.x;
  const int xcd = bid & 7, g = bid >> 3;            // 512 blocks
  const int nb = g & 3, mb = xcd * 16 + (g >> 2);   // mb 0..127
  const int m0 = mb * 64, n0 = nb * 64;
  const int wm = wave >> 1, wn = wave & 1;
  const int r = lane & 15, jj = lane >> 4;
  const int sr = tid >> 2, ssl = (tid & 3) * 8;
  const int arow = m0 + sr;                 // global m-row
  const int ab = arow >> 10, as = arow & 1023;
  const size_t rpbase = (size_t)ab * 8 * 1024 + as;   // + h*1024
  const f16* wsrc = wo16 + (size_t)(n0 + sr) * DM + ssl;

  auto mload = [&](int kk) -> f16x8 {
    const int h = kk >> 5;
    const size_t rp = rpbase + (size_t)h * 1024;
    const float2 ml1 = ((const float2*)mlpart)[rp];
    const float2 ml2 = ((const float2*)mlpart)[NROW + rp];
    const float M = fmaxf(ml1.x, ml2.x);
    const float s1 = fast_exp2(ml1.x - M);
    const float s2 = fast_exp2(ml2.x - M);
    const float inv = 1.f / (ml1.y * s1 + ml2.y * s2);
    f16x8 o1 = *(const f16x8*)(opart + rp * 32 + ssl);
    f16x8 o2 = *(const f16x8*)(opart + ((size_t)NROW + rp) * 32 + ssl);
    f16x8 o;
#pragma unroll
    for (int q = 0; q < 8; ++q)
      o[q] = (f16)(((float)o1[q] * s1 + (float)o2[q] * s2) * inv);
    return o;
  };

  f16x8 ra = mload(0);
  f16x8 rw = *(const f16x8*)(wsrc);
  f32x4 acc[2][2];
#pragma unroll
  for (int mi = 0; mi < 2; ++mi){
    acc[mi][0] = (f32x4){0.f,0.f,0.f,0.f};
    acc[mi][1] = (f32x4){0.f,0.f,0.f,0.f};
  }
  for (int kk = 0; kk < DM; kk += 32){
    __syncthreads();
    *(f16x8*)&AT[sr][ssl] = ra;
    *(f16x8*)&WO[sr][ssl] = rw;
    __syncthreads();
    if (kk + 32 < DM){
      ra = mload(kk + 32);
      rw = *(const f16x8*)(wsrc + kk + 32);
    }
    f16x8 bf0 = *(const f16x8*)&WO[wn * 32 + r][jj * 8];
    f16x8 bf1 = *(const f16x8*)&WO[wn * 32 + 16 + r][jj * 8];
#pragma unroll
    for (int mi = 0; mi < 2; ++mi){
      f16x8 af = *(const f16x8*)&AT[wm * 32 + mi * 16 + r][jj * 8];
      acc[mi][0] = mfma_f16_32(af, bf0, acc[mi][0]);
      acc[mi][1] = mfma_f16_32(af, bf1, acc[mi][1]);
    }
  }
#pragma unroll
  for (int ni = 0; ni < 2; ++ni){
    const int col = n0 + wn * 32 + ni * 16 + r;
    const float bc = bo[col];
#pragma unroll
    for (int mi = 0; mi < 2; ++mi){
#pragma unroll
      for (int rr = 0; rr < 4; ++rr){
        const int row = m0 + wm * 32 + mi * 16 + jj * 4 + rr;
        out[row * DM + col] = acc[mi][ni][rr] + bc;
      }
    }
  }
}

extern "C" void kernel_launch(void* const* d_in, const int* in_sizes, int n_in,
                              void* d_out, int out_size, void* d_ws, size_t ws_size,
                              hipStream_t stream){
  const float* hs = (const float*)d_in[0];
  const float* oq = (const float*)d_in[1];
  const float* Wq = (const float*)d_in[2];
  const float* bq = (const float*)d_in[3];
  const float* Wk = (const float*)d_in[4];
  const float* bk = (const float*)d_in[5];
  const float* Wv = (const float*)d_in[6];
  const float* bv = (const float*)d_in[7];
  const float* Wo = (const float*)d_in[8];
  const float* bo = (const float*)d_in[9];
  float* out = (float*)d_out;

  char* p = (char*)d_ws;
  auto alloc = [&](size_t bytes) -> char* {
    char* r = p;
    p += (bytes + 255) & ~((size_t)255);
    return r;
  };
  const size_t xb = (size_t)MTOT * DM * 2;  // 4 MiB per bf16/f16 plane
  unsigned short* qh = (unsigned short*)alloc(xb);
  unsigned short* ql = (unsigned short*)alloc(xb);
  unsigned short* kh = (unsigned short*)alloc(xb);
  unsigned short* kl = (unsigned short*)alloc(xb);
  f16* vT = (f16*)alloc(xb);
  const size_t wb = (size_t)DM * DM * 2;  // 128 KiB per weight plane
  unsigned short* wqh = (unsigned short*)alloc(wb);
  unsigned short* wql = (unsigned short*)alloc(wb);
  unsigned short* wkh = (unsigned short*)alloc(wb);
  unsigned short* wkl = (unsigned short*)alloc(wb);
  f16* wv16 = (f16*)alloc(wb);
  f16* wo16 = (f16*)alloc(wb);
  f16* opart = (f16*)alloc((size_t)2 * NROW * 32 * 2);      // 8 MiB
  float* mlpart = (float*)alloc((size_t)2 * NROW * 2 * 4);  // 1 MiB

  hipLaunchKernelGGL(prep_w_kernel, dim3(DM * DM / 256), dim3(256), 0, stream,
                     Wq, Wk, Wv, Wo, wqh, wql, wkh, wkl, wv16, wo16);
  hipLaunchKernelGGL(proj_qkv_kernel, dim3(256), dim3(256), 0, stream,
                     hs, oq, wqh, wql, wkh, wkl, wv16, bq, bk, bv,
                     qh, ql, kh, kl, vT);
  hipLaunchKernelGGL(attn_kernel, dim3(1024), dim3(256), 0, stream,
                     qh, ql, kh, kl, vT, opart, mlpart);
  hipLaunchKernelGGL(oproj_kernel, dim3(512), dim3(256), 0, stream,
                     opart, mlpart, wo16, bo, out);
}

// Round 13
// 61.706 us; speedup vs baseline: 1.0751x; 1.0570x over previous
//
#include <hip/hip_runtime.h>
#include <math.h>

#define BATCH 8
#define SEQ 1024
#define DM 256
#define NH 8
#define DH 32
#define MTOT (BATCH*SEQ)
#define LOG2E 1.4426950408889634f
#define SCALING 5.656854249492381f
#define QSCALE (SCALING * LOG2E)
#define NROW 65536              // 64 bh * 1024 ql
#define OSC 0.0625f             // partial-O scale (f16 headroom); cancels in merge

typedef __attribute__((ext_vector_type(8))) short short8;
typedef __attribute__((ext_vector_type(4))) float f32x4;
typedef _Float16 f16;
typedef __attribute__((ext_vector_type(8))) _Float16 f16x8;
typedef __attribute__((ext_vector_type(4))) _Float16 f16x4;

__device__ inline unsigned short f2bf(float f){
  union { float f; unsigned u; } x; x.f = f;
  unsigned r = x.u + 0x7fffu + ((x.u >> 16) & 1u);
  return (unsigned short)(r >> 16);
}
__device__ inline float bf2f(unsigned short s){
  union { unsigned u; float f; } x; x.u = ((unsigned)s) << 16;
  return x.f;
}
__device__ inline float u2f(unsigned u){
  union { unsigned u; float f; } x; x.u = u; return x.f;
}
__device__ inline unsigned cvtpk_bf16(float a, float b){
  unsigned r;
  asm("v_cvt_pk_bf16_f32 %0, %1, %2" : "=v"(r) : "v"(a), "v"(b));
  return r;  // low16 = bf16(a), high16 = bf16(b)
}
__device__ inline float fast_exp2(float x){
  float r; asm("v_exp_f32 %0, %1" : "=v"(r) : "v"(x)); return r;
}

__device__ inline f32x4 mfma_bf16(short8 a, short8 b, f32x4 c){
  return __builtin_amdgcn_mfma_f32_16x16x32_bf16(a, b, c, 0, 0, 0);
}
__device__ inline f32x4 mfma_f16_32(f16x8 a, f16x8 b, f32x4 c){
  return __builtin_amdgcn_mfma_f32_16x16x32_f16(a, b, c, 0, 0, 0);
}
__device__ inline f32x4 mfma_f16_16(f16x4 a, f16x4 b, f32x4 c){
  return __builtin_amdgcn_mfma_f32_16x16x16f16(a, b, c, 0, 0, 0);
}

// ---- prep: weight arrays --------------------------------------------------
__global__ __launch_bounds__(256) void prep_w_kernel(
    const float* __restrict__ Wq, const float* __restrict__ Wk,
    const float* __restrict__ Wv, const float* __restrict__ Wo,
    unsigned short* __restrict__ wqh, unsigned short* __restrict__ wql,
    unsigned short* __restrict__ wkh, unsigned short* __restrict__ wkl,
    f16* __restrict__ wv16, f16* __restrict__ wo16){
  int i = blockIdx.x * blockDim.x + threadIdx.x;
  if (i < DM * DM){
    float q = Wq[i];
    unsigned short qh_ = f2bf(q);
    wqh[i] = qh_; wql[i] = f2bf(q - bf2f(qh_));
    float k = Wk[i];
    unsigned short kh_ = f2bf(k);
    wkh[i] = kh_; wkl[i] = f2bf(k - bf2f(kh_));
    wv16[i] = (f16)Wv[i];
    wo16[i] = (f16)Wo[i];
  }
}

// ---- fused QKV projection: BM=64, BN=64 (2-3 blocks/CU for latency hiding) -
__global__ __launch_bounds__(256, 2) void proj_qkv_kernel(
    const float* __restrict__ hs, const float* __restrict__ oq,
    const unsigned short* __restrict__ wqh, const unsigned short* __restrict__ wql,
    const unsigned short* __restrict__ wkh, const unsigned short* __restrict__ wkl,
    const f16* __restrict__ wv16,
    const float* __restrict__ bq, const float* __restrict__ bk, const float* __restrict__ bv,
    unsigned short* __restrict__ qhp, unsigned short* __restrict__ qlp,
    unsigned short* __restrict__ khp, unsigned short* __restrict__ klp,
    f16* __restrict__ vT){
  __shared__ unsigned short XH[64][40];
  __shared__ unsigned short XL[64][40];
  __shared__ f16 XV[64][40];
  __shared__ unsigned short WQH[64][40];
  __shared__ unsigned short WQL[64][40];
  __shared__ unsigned short WKH[64][40];
  __shared__ unsigned short WKL[64][40];
  __shared__ f16 WV[64][40];
  __shared__ f16 VTT[64][72];
  const int tid = threadIdx.x;
  const int lane = tid & 63, wave = tid >> 6;
  const int bid = blockIdx.x;
  const int xcd = bid & 7, g = bid >> 3;            // 512 blocks
  const int nb = g & 3, mb = xcd * 16 + (g >> 2);   // mb 0..127
  const int m0 = mb * 64, n0 = nb * 64;
  const int wm = wave >> 1, wn = wave & 1;
  const int r = lane & 15, jj = lane >> 4;

  const int sr = tid >> 2, ssl = (tid & 3) * 8;
  const float* hs0 = hs + (size_t)(m0 + sr) * DM + ssl;
  const float* oq0 = oq + (size_t)(m0 + sr) * DM + ssl;
  const size_t wo = (size_t)(n0 + sr) * DM + ssl;

  auto convrow = [&](const float* hp, const float* op, int kk,
                     short8& xh, short8& xl, f16x8& xv){
    f32x4 ha = *(const f32x4*)(hp + kk);
    f32x4 hb = *(const f32x4*)(hp + kk + 4);
    f32x4 oa = *(const f32x4*)(op + kk);
    f32x4 ob = *(const f32x4*)(op + kk + 4);
    float p0 = ha[0]+oa[0], p1 = ha[1]+oa[1], p2 = ha[2]+oa[2], p3 = ha[3]+oa[3];
    float p4 = hb[0]+ob[0], p5 = hb[1]+ob[1], p6 = hb[2]+ob[2], p7 = hb[3]+ob[3];
    union { unsigned u[4]; short8 s; } H, L;
    H.u[0] = cvtpk_bf16(p0, p1); H.u[1] = cvtpk_bf16(p2, p3);
    H.u[2] = cvtpk_bf16(p4, p5); H.u[3] = cvtpk_bf16(p6, p7);
    float l0 = p0 - u2f(H.u[0] << 16), l1 = p1 - u2f(H.u[0] & 0xffff0000u);
    float l2 = p2 - u2f(H.u[1] << 16), l3 = p3 - u2f(H.u[1] & 0xffff0000u);
    float l4 = p4 - u2f(H.u[2] << 16), l5 = p5 - u2f(H.u[2] & 0xffff0000u);
    float l6 = p6 - u2f(H.u[3] << 16), l7 = p7 - u2f(H.u[3] & 0xffff0000u);
    L.u[0] = cvtpk_bf16(l0, l1); L.u[1] = cvtpk_bf16(l2, l3);
    L.u[2] = cvtpk_bf16(l4, l5); L.u[3] = cvtpk_bf16(l6, l7);
    xh = H.s; xl = L.s;
    f16x8 v;
    v[0]=(f16)ha[0]; v[1]=(f16)ha[1]; v[2]=(f16)ha[2]; v[3]=(f16)ha[3];
    v[4]=(f16)hb[0]; v[5]=(f16)hb[1]; v[6]=(f16)hb[2]; v[7]=(f16)hb[3];
    xv = v;
  };

  short8 sxh0, sxl0, rwq, rwql_, rwk, rwkl_;
  f16x8 sxv0, rwv;
  convrow(hs0, oq0, 0, sxh0, sxl0, sxv0);
  rwq = *(const short8*)(wqh + wo);   rwql_ = *(const short8*)(wql + wo);
  rwk = *(const short8*)(wkh + wo);   rwkl_ = *(const short8*)(wkl + wo);
  rwv = *(const f16x8*)(wv16 + wo);

  f32x4 aq[2][2], ak[2][2], av[2][2];
#pragma unroll
  for (int mi = 0; mi < 2; ++mi)
#pragma unroll
    for (int ni = 0; ni < 2; ++ni){
      aq[mi][ni] = (f32x4){0.f,0.f,0.f,0.f};
      ak[mi][ni] = (f32x4){0.f,0.f,0.f,0.f};
      av[mi][ni] = (f32x4){0.f,0.f,0.f,0.f};
    }

  for (int kk = 0; kk < DM; kk += 32){
    __syncthreads();
    *(short8*)&XH[sr][ssl] = sxh0;
    *(short8*)&XL[sr][ssl] = sxl0;
    *(f16x8*)&XV[sr][ssl] = sxv0;
    *(short8*)&WQH[sr][ssl] = rwq;  *(short8*)&WQL[sr][ssl] = rwql_;
    *(short8*)&WKH[sr][ssl] = rwk;  *(short8*)&WKL[sr][ssl] = rwkl_;
    *(f16x8*)&WV[sr][ssl] = rwv;
    __syncthreads();
    if (kk + 32 < DM){
      const int o = kk + 32;
      convrow(hs0, oq0, o, sxh0, sxl0, sxv0);
      rwq = *(const short8*)(wqh + wo + o);   rwql_ = *(const short8*)(wql + wo + o);
      rwk = *(const short8*)(wkh + wo + o);   rwkl_ = *(const short8*)(wkl + wo + o);
      rwv = *(const f16x8*)(wv16 + wo + o);
    }
#pragma unroll
    for (int ni = 0; ni < 2; ++ni){
      const int brow = wn * 32 + ni * 16 + r;
      short8 bwqh = *(const short8*)&WQH[brow][jj * 8];
      short8 bwql = *(const short8*)&WQL[brow][jj * 8];
      short8 bwkh = *(const short8*)&WKH[brow][jj * 8];
      short8 bwkl = *(const short8*)&WKL[brow][jj * 8];
      f16x8 bwv = *(const f16x8*)&WV[brow][jj * 8];
#pragma unroll
      for (int mi = 0; mi < 2; ++mi){
        const int arow = wm * 32 + mi * 16 + r;
        short8 axh = *(const short8*)&XH[arow][jj * 8];
        short8 axl = *(const short8*)&XL[arow][jj * 8];
        f16x8 axv = *(const f16x8*)&XV[arow][jj * 8];
        aq[mi][ni] = mfma_bf16(axh, bwqh, aq[mi][ni]);
        aq[mi][ni] = mfma_bf16(axh, bwql, aq[mi][ni]);
        aq[mi][ni] = mfma_bf16(axl, bwqh, aq[mi][ni]);
        ak[mi][ni] = mfma_bf16(axh, bwkh, ak[mi][ni]);
        ak[mi][ni] = mfma_bf16(axh, bwkl, ak[mi][ni]);
        ak[mi][ni] = mfma_bf16(axl, bwkh, ak[mi][ni]);
        av[mi][ni] = mfma_f16_32(axv, bwv, av[mi][ni]);
      }
    }
  }
  // epilogue: Q/K direct; V into LDS transpose buffer (bias applied here)
#pragma unroll
  for (int ni = 0; ni < 2; ++ni){
    const int col = n0 + wn * 32 + ni * 16 + r;
    const float bqc = bq[col] * QSCALE;
    const float bkc = bk[col];
    const float bvc = bv[col];
#pragma unroll
    for (int mi = 0; mi < 2; ++mi){
      f16x4 v4;
#pragma unroll
      for (int rr = 0; rr < 4; ++rr){
        const int row = m0 + wm * 32 + mi * 16 + jj * 4 + rr;
        float qv = aq[mi][ni][rr] * QSCALE + bqc;
        unsigned short qhi = f2bf(qv);
        qhp[row * DM + col] = qhi;
        qlp[row * DM + col] = f2bf(qv - bf2f(qhi));
        float kv = ak[mi][ni][rr] + bkc;
        unsigned short khi = f2bf(kv);
        khp[row * DM + col] = khi;
        klp[row * DM + col] = f2bf(kv - bf2f(khi));
        v4[rr] = (f16)(av[mi][ni][rr] + bvc);
      }
      *(f16x4*)&VTT[wn * 32 + ni * 16 + r][wm * 32 + mi * 16 + jj * 4] = v4;
    }
  }
  __syncthreads();
  // coalesced vT write: 64 cols x 64 s per block (block never crosses batch)
  const int batch = m0 >> 10;
  const int s0 = m0 & 1023;
  const int c = tid >> 2, sblk = (tid & 3) * 16;
  f16* dst = vT + ((size_t)(batch * DM + n0 + c)) * SEQ + s0 + sblk;
  *(f16x8*)(dst) = *(const f16x8*)&VTT[c][sblk];
  *(f16x8*)(dst + 8) = *(const f16x8*)&VTT[c][sblk + 8];
}

// ---- flash attention: key-split x2, 32 q-rows/wave, XCD-pinned ------------
__global__ __launch_bounds__(256, 3) void attn_kernel(
    const unsigned short* __restrict__ qh, const unsigned short* __restrict__ ql,
    const unsigned short* __restrict__ kh, const unsigned short* __restrict__ kl,
    const f16* __restrict__ vT, f16* __restrict__ opart, float* __restrict__ mlpart){
  __shared__ unsigned short KH[2][64][40];
  __shared__ unsigned short KL[2][64][40];
  __shared__ f16 VT[2][32][72];
  const int lane = threadIdx.x & 63;
  const int wave = threadIdx.x >> 6;
  const int tid = threadIdx.x;
  const int xcd = blockIdx.x & 7, j = blockIdx.x >> 3;   // j: 0..127
  const int bh = xcd * 8 + (j & 7);
  const int u = j >> 3;                  // 0..15
  const int qb = u & 7, half = u >> 3;
  const int b = bh >> 3, h = bh & 7;
  const int q0 = (qb * 4 + wave) * 32;
  const int rowbase = b * SEQ;
  const int kbase = rowbase + half * 512;
  const int col0 = h * DH;
  const int r = lane & 15, jj = lane >> 4;

  const int qrowA = rowbase + q0 + r;
  const int qrowB = qrowA + 16;
  short8 bqhA = *(const short8*)(qh + qrowA * DM + col0 + jj * 8);
  short8 bqlA = *(const short8*)(ql + qrowA * DM + col0 + jj * 8);
  short8 bqhB = *(const short8*)(qh + qrowB * DM + col0 + jj * 8);
  short8 bqlB = *(const short8*)(ql + qrowB * DM + col0 + jj * 8);

  const int skey = tid >> 2, ssl = tid & 3;
  const unsigned short* khsrc = kh + (size_t)(kbase + skey) * DM + col0 + ssl * 8;
  const unsigned short* klsrc = kl + (size_t)(kbase + skey) * DM + col0 + ssl * 8;
  const int sdh = tid >> 3, ss8 = tid & 7;
  const f16* vsrc = vT + (size_t)(b * DM + col0 + sdh) * SEQ + half * 512 + ss8 * 8;

  short8 rkh = *(const short8*)(khsrc);
  short8 rkl = *(const short8*)(klsrc);
  f16x8 rv = *(const f16x8*)(vsrc);

  float mA = -INFINITY, lsumA = 0.f;
  float mB = -INFINITY, lsumB = 0.f;
  f32x4 o0a = {0.f,0.f,0.f,0.f}, o1a = {0.f,0.f,0.f,0.f};
  f32x4 o0b = {0.f,0.f,0.f,0.f}, o1b = {0.f,0.f,0.f,0.f};

  for (int c = 0; c < 512; c += 64){
    const int p = (c >> 6) & 1;
    *(short8*)&KH[p][skey][ssl * 8] = rkh;
    *(short8*)&KL[p][skey][ssl * 8] = rkl;
    *(f16x8*)&VT[p][sdh][ss8 * 8] = rv;
    __syncthreads();
    if (c + 64 < 512){
      rkh = *(const short8*)(khsrc + (size_t)(c + 64) * DM);
      rkl = *(const short8*)(klsrc + (size_t)(c + 64) * DM);
      rv = *(const f16x8*)(vsrc + c + 64);
    }
    f32x4 sA[4], sB[4];
    float cmaxA = -INFINITY, cmaxB = -INFINITY;
#pragma unroll
    for (int t = 0; t < 4; ++t){
      short8 akh = *(const short8*)&KH[p][t * 16 + r][jj * 8];
      short8 akl = *(const short8*)&KL[p][t * 16 + r][jj * 8];
      f32x4 sv = {0.f,0.f,0.f,0.f};
      sv = mfma_bf16(akh, bqhA, sv);
      sv = mfma_bf16(akh, bqlA, sv);
      sv = mfma_bf16(akl, bqhA, sv);
      sA[t] = sv;
      cmaxA = fmaxf(cmaxA, fmaxf(fmaxf(sv[0], sv[1]), fmaxf(sv[2], sv[3])));
      f32x4 sw = {0.f,0.f,0.f,0.f};
      sw = mfma_bf16(akh, bqhB, sw);
      sw = mfma_bf16(akh, bqlB, sw);
      sw = mfma_bf16(akl, bqhB, sw);
      sB[t] = sw;
      cmaxB = fmaxf(cmaxB, fmaxf(fmaxf(sw[0], sw[1]), fmaxf(sw[2], sw[3])));
    }
    cmaxA = fmaxf(cmaxA, __shfl_xor(cmaxA, 16, 64));
    cmaxA = fmaxf(cmaxA, __shfl_xor(cmaxA, 32, 64));
    cmaxB = fmaxf(cmaxB, __shfl_xor(cmaxB, 16, 64));
    cmaxB = fmaxf(cmaxB, __shfl_xor(cmaxB, 32, 64));
    if (!__all(cmaxA - mA <= 8.0f)){
      const float mnew = fmaxf(mA, cmaxA);
      const float scale = fast_exp2(mA - mnew);
      lsumA *= scale;
#pragma unroll
      for (int rr = 0; rr < 4; ++rr){ o0a[rr] *= scale; o1a[rr] *= scale; }
      mA = mnew;
    }
    if (!__all(cmaxB - mB <= 8.0f)){
      const float mnew = fmaxf(mB, cmaxB);
      const float scale = fast_exp2(mB - mnew);
      lsumB *= scale;
#pragma unroll
      for (int rr = 0; rr < 4; ++rr){ o0b[rr] *= scale; o1b[rr] *= scale; }
      mB = mnew;
    }
    float psA = 0.f, psB = 0.f;
    f16x4 bpA[4], bpB[4];
#pragma unroll
    for (int t = 0; t < 4; ++t){
      float a0 = fast_exp2(sA[t][0] - mA);
      float a1 = fast_exp2(sA[t][1] - mA);
      float a2 = fast_exp2(sA[t][2] - mA);
      float a3 = fast_exp2(sA[t][3] - mA);
      psA += (a0 + a1) + (a2 + a3);
      f16x4 ba; ba[0]=(f16)a0; ba[1]=(f16)a1; ba[2]=(f16)a2; ba[3]=(f16)a3;
      bpA[t] = ba;
      float b0 = fast_exp2(sB[t][0] - mB);
      float b1 = fast_exp2(sB[t][1] - mB);
      float b2 = fast_exp2(sB[t][2] - mB);
      float b3 = fast_exp2(sB[t][3] - mB);
      psB += (b0 + b1) + (b2 + b3);
      f16x4 bb; bb[0]=(f16)b0; bb[1]=(f16)b1; bb[2]=(f16)b2; bb[3]=(f16)b3;
      bpB[t] = bb;
    }
    psA += __shfl_xor(psA, 16, 64);
    psA += __shfl_xor(psA, 32, 64);
    lsumA += psA;
    psB += __shfl_xor(psB, 16, 64);
    psB += __shfl_xor(psB, 32, 64);
    lsumB += psB;
#pragma unroll
    for (int t = 0; t < 4; ++t){
      f16x4 av0 = *(const f16x4*)&VT[p][r][t * 16 + jj * 4];
      f16x4 av1 = *(const f16x4*)&VT[p][16 + r][t * 16 + jj * 4];
      o0a = mfma_f16_16(av0, bpA[t], o0a);
      o1a = mfma_f16_16(av1, bpA[t], o1a);
      o0b = mfma_f16_16(av0, bpB[t], o0b);
      o1b = mfma_f16_16(av1, bpB[t], o1b);
    }
  }
  const size_t prowA = (size_t)(half * NROW + bh * 1024 + q0 + r);
  const size_t prowB = prowA + 16;
  f16x4 w0a, w1a, w0b, w1b;
#pragma unroll
  for (int rr = 0; rr < 4; ++rr){
    w0a[rr] = (f16)(o0a[rr] * OSC); w1a[rr] = (f16)(o1a[rr] * OSC);
    w0b[rr] = (f16)(o0b[rr] * OSC); w1b[rr] = (f16)(o1b[rr] * OSC);
  }
  *(f16x4*)(opart + prowA * 32 + jj * 4) = w0a;
  *(f16x4*)(opart + prowA * 32 + 16 + jj * 4) = w1a;
  *(f16x4*)(opart + prowB * 32 + jj * 4) = w0b;
  *(f16x4*)(opart + prowB * 32 + 16 + jj * 4) = w1b;
  if (jj == 0){
    ((float2*)mlpart)[prowA] = make_float2(mA, lsumA * OSC);
    ((float2*)mlpart)[prowB] = make_float2(mB, lsumB * OSC);
  }
}

// ---- output projection with fused key-half merge ---------------------------
__global__ __launch_bounds__(256, 4) void oproj_kernel(
    const f16* __restrict__ opart, const float* __restrict__ mlpart,
    const f16* __restrict__ wo16,
    const float* __restrict__ bo, float* __restrict__ out){
  __shared__ f16 AT[64][40];
  __shared__ f16 WO[64][40];
  const int tid = threadIdx.x;
  const int lane = tid & 63, wave = tid >> 6;
  const int bid = blockIdx.x;
  const int xcd = bid & 7, g = bid >> 3;            // 512 blocks
  const int nb = g & 3, mb = xcd * 16 + (g >> 2);   // mb 0..127
  const int m0 = mb * 64, n0 = nb * 64;
  const int wm = wave >> 1, wn = wave & 1;
  const int r = lane & 15, jj = lane >> 4;
  const int sr = tid >> 2, ssl = (tid & 3) * 8;
  const int arow = m0 + sr;                 // global m-row
  const int ab = arow >> 10, as = arow & 1023;
  const size_t rpbase = (size_t)ab * 8 * 1024 + as;   // + h*1024
  const f16* wsrc = wo16 + (size_t)(n0 + sr) * DM + ssl;

  auto mload = [&](int kk) -> f16x8 {
    const int h = kk >> 5;
    const size_t rp = rpbase + (size_t)h * 1024;
    const float2 ml1 = ((const float2*)mlpart)[rp];
    const float2 ml2 = ((const float2*)mlpart)[NROW + rp];
    const float M = fmaxf(ml1.x, ml2.x);
    const float s1 = fast_exp2(ml1.x - M);
    const float s2 = fast_exp2(ml2.x - M);
    const float inv = 1.f / (ml1.y * s1 + ml2.y * s2);
    f16x8 o1 = *(const f16x8*)(opart + rp * 32 + ssl);
    f16x8 o2 = *(const f16x8*)(opart + ((size_t)NROW + rp) * 32 + ssl);
    f16x8 o;
#pragma unroll
    for (int q = 0; q < 8; ++q)
      o[q] = (f16)(((float)o1[q] * s1 + (float)o2[q] * s2) * inv);
    return o;
  };

  f16x8 ra = mload(0);
  f16x8 rw = *(const f16x8*)(wsrc);
  f32x4 acc[2][2];
#pragma unroll
  for (int mi = 0; mi < 2; ++mi){
    acc[mi][0] = (f32x4){0.f,0.f,0.f,0.f};
    acc[mi][1] = (f32x4){0.f,0.f,0.f,0.f};
  }
  for (int kk = 0; kk < DM; kk += 32){
    __syncthreads();
    *(f16x8*)&AT[sr][ssl] = ra;
    *(f16x8*)&WO[sr][ssl] = rw;
    __syncthreads();
    if (kk + 32 < DM){
      ra = mload(kk + 32);
      rw = *(const f16x8*)(wsrc + kk + 32);
    }
    f16x8 bf0 = *(const f16x8*)&WO[wn * 32 + r][jj * 8];
    f16x8 bf1 = *(const f16x8*)&WO[wn * 32 + 16 + r][jj * 8];
#pragma unroll
    for (int mi = 0; mi < 2; ++mi){
      f16x8 af = *(const f16x8*)&AT[wm * 32 + mi * 16 + r][jj * 8];
      acc[mi][0] = mfma_f16_32(af, bf0, acc[mi][0]);
      acc[mi][1] = mfma_f16_32(af, bf1, acc[mi][1]);
    }
  }
#pragma unroll
  for (int ni = 0; ni < 2; ++ni){
    const int col = n0 + wn * 32 + ni * 16 + r;
    const float bc = bo[col];
#pragma unroll
    for (int mi = 0; mi < 2; ++mi){
#pragma unroll
      for (int rr = 0; rr < 4; ++rr){
        const int row = m0 + wm * 32 + mi * 16 + jj * 4 + rr;
        out[row * DM + col] = acc[mi][ni][rr] + bc;
      }
    }
  }
}

extern "C" void kernel_launch(void* const* d_in, const int* in_sizes, int n_in,
                              void* d_out, int out_size, void* d_ws, size_t ws_size,
                              hipStream_t stream){
  const float* hs = (const float*)d_in[0];
  const float* oq = (const float*)d_in[1];
  const float* Wq = (const float*)d_in[2];
  const float* bq = (const float*)d_in[3];
  const float* Wk = (const float*)d_in[4];
  const float* bk = (const float*)d_in[5];
  const float* Wv = (const float*)d_in[6];
  const float* bv = (const float*)d_in[7];
  const float* Wo = (const float*)d_in[8];
  const float* bo = (const float*)d_in[9];
  float* out = (float*)d_out;

  char* p = (char*)d_ws;
  auto alloc = [&](size_t bytes) -> char* {
    char* r = p;
    p += (bytes + 255) & ~((size_t)255);
    return r;
  };
  const size_t xb = (size_t)MTOT * DM * 2;  // 4 MiB per bf16/f16 plane
  unsigned short* qh = (unsigned short*)alloc(xb);
  unsigned short* ql = (unsigned short*)alloc(xb);
  unsigned short* kh = (unsigned short*)alloc(xb);
  unsigned short* kl = (unsigned short*)alloc(xb);
  f16* vT = (f16*)alloc(xb);
  const size_t wb = (size_t)DM * DM * 2;  // 128 KiB per weight plane
  unsigned short* wqh = (unsigned short*)alloc(wb);
  unsigned short* wql = (unsigned short*)alloc(wb);
  unsigned short* wkh = (unsigned short*)alloc(wb);
  unsigned short* wkl = (unsigned short*)alloc(wb);
  f16* wv16 = (f16*)alloc(wb);
  f16* wo16 = (f16*)alloc(wb);
  f16* opart = (f16*)alloc((size_t)2 * NROW * 32 * 2);      // 8 MiB
  float* mlpart = (float*)alloc((size_t)2 * NROW * 2 * 4);  // 1 MiB

  hipLaunchKernelGGL(prep_w_kernel, dim3(DM * DM / 256), dim3(256), 0, stream,
                     Wq, Wk, Wv, Wo, wqh, wql, wkh, wkl, wv16, wo16);
  hipLaunchKernelGGL(proj_qkv_kernel, dim3(512), dim3(256), 0, stream,
                     hs, oq, wqh, wql, wkh, wkl, wv16, bq, bk, bv,
                     qh, ql, kh, kl, vT);
  hipLaunchKernelGGL(attn_kernel, dim3(1024), dim3(256), 0, stream,
                     qh, ql, kh, kl, vT, opart, mlpart);
  hipLaunchKernelGGL(oproj_kernel, dim3(512), dim3(256), 0, stream,
                     opart, mlpart, wo16, bo, out);
}